// Round 3
// baseline (1269.290 us; speedup 1.0000x reference)
//
#include <hip/hip_runtime.h>

#define NG 1024
#define GN_EPS 1e-5f

__device__ __forceinline__ float bf2f(unsigned short u) {
  union { float f; unsigned int i; } c;
  c.i = ((unsigned int)u) << 16;
  return c.f;
}
__device__ __forceinline__ unsigned short f2bf(float f) {
  union { float f; unsigned int i; } c;
  c.f = f;
  unsigned int b = c.i;
  b += 0x7fffu + ((b >> 16) & 1u);  // RNE
  return (unsigned short)(b >> 16);
}
__device__ __forceinline__ void f4red(float4& a, int mask) {
  a.x += __shfl_xor(a.x, mask);
  a.y += __shfl_xor(a.y, mask);
  a.z += __shfl_xor(a.z, mask);
  a.w += __shfl_xor(a.w, mask);
}

// ---------------- graph boundaries from sorted batch ----------------
__global__ void k_bounds(const int* __restrict__ batch, int* __restrict__ goff, int N) {
  int i = blockIdx.x * blockDim.x + threadIdx.x;
  if (i >= N) return;
  int b = batch[i];
  int pb = (i == 0) ? -1 : batch[i - 1];
  for (int g = pb + 1; g <= b; ++g) goff[g] = i;
  if (i == N - 1) {
    for (int g = b + 1; g <= NG; ++g) goff[g] = N;
  }
}

// ---------------- bucketed CSR build ----------------
// bucket b covers nodes [128b, 128b+128); B = N/128 + 1 <= 1024
__global__ void k_hist(const int* __restrict__ dst, int* __restrict__ bucketCnt,
                       int E, int B) {
  __shared__ int h[1024];
  for (int i = threadIdx.x; i < B; i += 256) h[i] = 0;
  __syncthreads();
  for (int e = blockIdx.x * 256 + threadIdx.x; e < E; e += gridDim.x * 256)
    atomicAdd(&h[dst[e] >> 7], 1);
  __syncthreads();
  for (int i = threadIdx.x; i < B; i += 256)
    if (h[i]) atomicAdd(&bucketCnt[i], h[i]);
}

__global__ void k_bscan(const int* __restrict__ bucketCnt, int* __restrict__ bucketOff,
                        int* __restrict__ bucketCur, int B) {
  __shared__ int lds[1024];
  int t = threadIdx.x;
  int v = (t < B) ? bucketCnt[t] : 0;
  lds[t] = v;
  __syncthreads();
  for (int off = 1; off < 1024; off <<= 1) {
    int u = (t >= off) ? lds[t - off] : 0;
    __syncthreads();
    lds[t] += u;
    __syncthreads();
  }
  if (t < B) {
    int ex = lds[t] - v;
    bucketOff[t] = ex;
    bucketCur[t] = ex;
  }
}

__global__ void k_scatter(const int* __restrict__ src, const int* __restrict__ dst,
                          int* __restrict__ bucketCur,
                          unsigned long long* __restrict__ ebuf, int E) {
  int e = blockIdx.x * 256 + threadIdx.x;
  if (e >= E) return;
  int d = dst[e];
  int pos = atomicAdd(&bucketCur[d >> 7], 1);
  ebuf[pos] = ((unsigned long long)(unsigned int)d << 32) | (unsigned int)src[e];
}

// one block per bucket: local degree hist + scan in LDS -> rowptr; scatter col
// within the bucket's ~16KB L2-resident slice.
__global__ void k_bucket_fill(const unsigned long long* __restrict__ ebuf,
                              const int* __restrict__ bucketOff,
                              int* __restrict__ rowptr, int* __restrict__ col,
                              int N, int E, int B) {
  __shared__ int deg[128];
  __shared__ int cur[128];
  int b = blockIdx.x;
  int s = bucketOff[b];
  int e = (b + 1 < B) ? bucketOff[b + 1] : E;
  int t = threadIdx.x;
  int base = b << 7;
  if (t < 128) deg[t] = 0;
  __syncthreads();
  for (int k = s + t; k < e; k += 256) {
    int d = (int)(ebuf[k] >> 32);
    atomicAdd(&deg[d - base], 1);
  }
  __syncthreads();
  if (t == 0) {
    int acc = s;
    for (int i = 0; i < 128; ++i) {
      int d = deg[i];
      deg[i] = acc;
      acc += d;
    }
  }
  __syncthreads();
  if (t < 128) {
    cur[t] = deg[t];
    int idx = base + t;
    if (idx <= N) rowptr[idx] = deg[t];
  }
  __syncthreads();
  for (int k = s + t; k < e; k += 256) {
    unsigned long long p = ebuf[k];
    int d = (int)(p >> 32) - base;
    int sv = (int)(p & 0xffffffffu);
    int pos = atomicAdd(&cur[d], 1);
    col[pos] = sv;
  }
}

// ---------------- GraphNorm: f32 out + bf16 mirror for the gather ----------------
template <int F>
__global__ void k_gn(const float* x, float* out, unsigned short* outbf,
                     const int* __restrict__ goff,
                     const float* __restrict__ w, const float* __restrict__ b,
                     const float* __restrict__ ms) {
  constexpr int NPW = 256 / F;
  __shared__ float r1[256], r2[256];
  __shared__ float sA[F], sB[F];
  int g = blockIdx.x;
  int s = goff[g], e = goff[g + 1];
  int t = threadIdx.x;
  int f = t % F, sub = t / F;
  float s1 = 0.f, s2 = 0.f;
  for (int i = s + sub; i < e; i += NPW) {
    float v = x[i * F + f];
    s1 += v;
    s2 += v * v;
  }
  r1[t] = s1;
  r2[t] = s2;
  __syncthreads();
  if (t < F) {
    float S1 = 0.f, S2 = 0.f;
    for (int k = 0; k < NPW; ++k) {
      S1 += r1[k * F + t];
      S2 += r2[k * F + t];
    }
    float cnt = (float)max(e - s, 1);
    float mean = S1 / cnt, m2 = S2 / cnt;
    float m = ms[t];
    float var = m2 + mean * mean * m * (m - 2.f);  // E[(x-mean*ms)^2]
    float rsq = rsqrtf(var + GN_EPS);
    float Av = w[t] * rsq;
    sA[t] = Av;
    sB[t] = b[t] - mean * m * Av;
  }
  __syncthreads();
  float Af = sA[f], Bf = sB[f];
  for (int i = s + sub; i < e; i += NPW) {
    float v = x[i * F + f] * Af + Bf;
    out[i * F + f] = v;
    outbf[i * F + f] = f2bf(v);
  }
}

// ---------------- GraphConv ----------------
// gather reads bf16 mirror (8B/lane), accumulates f32; root + matvec in f32.
template <int FIN>
__global__ __launch_bounds__(256) void k_conv(
    const float* __restrict__ hin, const unsigned short* __restrict__ hbf,
    float* __restrict__ hout,
    const int* __restrict__ rowptr, const int* __restrict__ col,
    const float* __restrict__ wrel, const float* __restrict__ brel,
    const float* __restrict__ wroot, int N) {
  constexpr int PAD = FIN + 4;
  constexpr int NSLOT = (FIN == 64) ? 4 : 16;
  __shared__ float aggL[64 * PAD];
  int tile = blockIdx.x;
  int lane = threadIdx.x & 63;
  int w = __builtin_amdgcn_readfirstlane(threadIdx.x >> 6);

  int q = (FIN == 64) ? (lane & 15) : (lane & 3);   // quad of 4 features
  int slot = (FIN == 64) ? (lane >> 4) : (lane >> 2);

  for (int nl = 0; nl < 16; ++nl) {
    int r = w * 16 + nl;
    int n = tile * 64 + r;
    float4 a0 = make_float4(0.f, 0.f, 0.f, 0.f);
    float4 a1 = make_float4(0.f, 0.f, 0.f, 0.f);
    if (n < N) {
      int s = rowptr[n], e = rowptr[n + 1];
      int k = s + slot;
      for (; k + NSLOT < e; k += 2 * NSLOT) {
        int nb0 = col[k];
        int nb1 = col[k + NSLOT];
        ushort4 v0 = *(const ushort4*)&hbf[(size_t)nb0 * FIN + q * 4];
        ushort4 v1 = *(const ushort4*)&hbf[(size_t)nb1 * FIN + q * 4];
        a0.x += bf2f(v0.x); a0.y += bf2f(v0.y); a0.z += bf2f(v0.z); a0.w += bf2f(v0.w);
        a1.x += bf2f(v1.x); a1.y += bf2f(v1.y); a1.z += bf2f(v1.z); a1.w += bf2f(v1.w);
      }
      if (k < e) {
        int nb = col[k];
        ushort4 v = *(const ushort4*)&hbf[(size_t)nb * FIN + q * 4];
        a0.x += bf2f(v.x); a0.y += bf2f(v.y); a0.z += bf2f(v.z); a0.w += bf2f(v.w);
      }
    }
    a0.x += a1.x; a0.y += a1.y; a0.z += a1.z; a0.w += a1.w;
    if (FIN == 64) {
      f4red(a0, 16);
      f4red(a0, 32);
    } else {
      f4red(a0, 4);
      f4red(a0, 8);
      f4red(a0, 16);
      f4red(a0, 32);
    }
    if (slot == 0) *(float4*)&aggL[r * PAD + q * 4] = a0;
  }
  __syncthreads();

  int n = tile * 64 + lane;
  if (n >= N) return;
  int wbase = w * 16;
  float accR[16], accT[16];
#pragma unroll
  for (int j = 0; j < 16; ++j) {
    accR[j] = 0.f;
    accT[j] = 0.f;
  }
#pragma unroll 2
  for (int fq = 0; fq < FIN / 4; ++fq) {
    float4 qa = *(const float4*)&aggL[lane * PAD + fq * 4];
    float4 qh = *(const float4*)&hin[(size_t)n * FIN + fq * 4];
#pragma unroll
    for (int j = 0; j < 16; ++j) {
      int o = wbase + j;
      const float* wr = &wrel[o * FIN + fq * 4];
      const float* wt = &wroot[o * FIN + fq * 4];
      accR[j] += wr[0] * qa.x + wr[1] * qa.y + wr[2] * qa.z + wr[3] * qa.w;
      accT[j] += wt[0] * qh.x + wt[1] * qh.y + wt[2] * qh.z + wt[3] * qh.w;
    }
  }
#pragma unroll
  for (int qq = 0; qq < 4; ++qq) {
    float4 rv;
    float* rr = (float*)&rv;
#pragma unroll
    for (int jj = 0; jj < 4; ++jj) {
      int j = qq * 4 + jj;
      float v = accR[j] + accT[j] + brel[wbase + j];
      rr[jj] = fmaxf(v, 0.f);
    }
    *(float4*)&hout[(size_t)n * 64 + wbase + qq * 4] = rv;
  }
}

// ---------------- mean-pool + dense(relu) + out + softmax ----------------
__global__ void k_final(const float* __restrict__ h, const int* __restrict__ goff,
                        const float* __restrict__ dw, const float* __restrict__ db,
                        const float* __restrict__ ow, const float* __restrict__ ob,
                        float* __restrict__ out) {
  __shared__ float red[256];
  __shared__ float pl[64];
  __shared__ float gl[64];
  int g = blockIdx.x;
  int s = goff[g], e = goff[g + 1];
  int t = threadIdx.x;
  int f = t & 63, sub = t >> 6;
  float s1 = 0.f;
  for (int i = s + sub; i < e; i += 4) s1 += h[i * 64 + f];
  red[t] = s1;
  __syncthreads();
  if (t < 64) {
    float S = red[t] + red[64 + t] + red[128 + t] + red[192 + t];
    float cnt = (float)max(e - s, 1);
    pl[t] = S / cnt;
  }
  __syncthreads();
  if (t < 64) {
    float acc = db[t];
#pragma unroll 8
    for (int k = 0; k < 64; ++k) acc += dw[t * 64 + k] * pl[k];
    gl[t] = fmaxf(acc, 0.f);
  }
  __syncthreads();
  if (t == 0) {
    float l0 = ob[0], l1 = ob[1];
    for (int k = 0; k < 64; ++k) {
      l0 += ow[k] * gl[k];
      l1 += ow[64 + k] * gl[k];
    }
    float m = fmaxf(l0, l1);
    float e0 = expf(l0 - m), e1 = expf(l1 - m);
    float inv = 1.f / (e0 + e1);
    out[g * 2 + 0] = e0 * inv;
    out[g * 2 + 1] = e1 * inv;
  }
}

extern "C" void kernel_launch(void* const* d_in, const int* in_sizes, int n_in,
                              void* d_out, int out_size, void* d_ws, size_t ws_size,
                              hipStream_t stream) {
  const float* x = (const float*)d_in[0];
  const int* ei = (const int*)d_in[1];
  const int* batch = (const int*)d_in[2];
  const float* gn0_w = (const float*)d_in[3];
  const float* gn0_b = (const float*)d_in[4];
  const float* gn0_ms = (const float*)d_in[5];
  const float* gn1_w = (const float*)d_in[6];
  const float* gn1_b = (const float*)d_in[7];
  const float* gn1_ms = (const float*)d_in[8];
  const float* gn2_w = (const float*)d_in[9];
  const float* gn2_b = (const float*)d_in[10];
  const float* gn2_ms = (const float*)d_in[11];
  const float* w1_rel = (const float*)d_in[12];
  const float* b1 = (const float*)d_in[13];
  const float* w1_root = (const float*)d_in[14];
  const float* w2_rel = (const float*)d_in[15];
  const float* b2 = (const float*)d_in[16];
  const float* w2_root = (const float*)d_in[17];
  const float* w3_rel = (const float*)d_in[18];
  const float* b3 = (const float*)d_in[19];
  const float* w3_root = (const float*)d_in[20];
  const float* dense_w = (const float*)d_in[21];
  const float* dense_b = (const float*)d_in[22];
  const float* out_w = (const float*)d_in[23];
  const float* out_b = (const float*)d_in[24];

  int N = in_sizes[2];
  int E = in_sizes[1] / 2;
  int B = (N >> 7) + 1;  // buckets of 128 nodes; covers node N for rowptr

  char* ws = (char*)d_ws;
  auto alloc = [&](size_t bytes) {
    char* p = ws;
    ws += (bytes + 255) & ~(size_t)255;
    return p;
  };
  int* rowptr = (int*)alloc(((size_t)N + 1) * 4);
  int* goff = (int*)alloc((NG + 1) * 4);
  int* bucketCnt = (int*)alloc((size_t)B * 4);
  int* bucketOff = (int*)alloc((size_t)B * 4);
  int* bucketCur = (int*)alloc((size_t)B * 4);
  int* col = (int*)alloc((size_t)E * 4);
  size_t hbytes = (size_t)N * 64 * 4;
  size_t ebytes = (size_t)E * 8;
  char* hA_raw = (char*)alloc(hbytes > ebytes ? hbytes : ebytes);  // hA aliases ebuf
  float* hA = (float*)hA_raw;
  unsigned long long* ebuf = (unsigned long long*)hA_raw;
  float* hB = (float*)alloc(hbytes);
  unsigned short* hbf = (unsigned short*)alloc((size_t)N * 64 * 2);  // shared bf16 mirror

  const int* src = ei;
  const int* dst = ei + E;

  hipMemsetAsync(bucketCnt, 0, (size_t)B * 4, stream);
  k_bounds<<<(N + 255) / 256, 256, 0, stream>>>(batch, goff, N);
  k_hist<<<256, 256, 0, stream>>>(dst, bucketCnt, E, B);
  k_bscan<<<1, 1024, 0, stream>>>(bucketCnt, bucketOff, bucketCur, B);
  k_scatter<<<(E + 255) / 256, 256, 0, stream>>>(src, dst, bucketCur, ebuf, E);
  k_bucket_fill<<<B, 256, 0, stream>>>(ebuf, bucketOff, rowptr, col, N, E, B);

  int tiles = (N + 63) / 64;
  k_gn<16><<<NG, 256, 0, stream>>>(x, hA, hbf, goff, gn0_w, gn0_b, gn0_ms);
  k_conv<16><<<tiles, 256, 0, stream>>>(hA, hbf, hB, rowptr, col, w1_rel, b1, w1_root, N);
  k_gn<64><<<NG, 256, 0, stream>>>(hB, hB, hbf, goff, gn1_w, gn1_b, gn1_ms);
  k_conv<64><<<tiles, 256, 0, stream>>>(hB, hbf, hA, rowptr, col, w2_rel, b2, w2_root, N);
  k_gn<64><<<NG, 256, 0, stream>>>(hA, hA, hbf, goff, gn2_w, gn2_b, gn2_ms);
  k_conv<64><<<tiles, 256, 0, stream>>>(hA, hbf, hB, rowptr, col, w3_rel, b3, w3_root, N);
  k_final<<<NG, 256, 0, stream>>>(hB, goff, dense_w, dense_b, out_w, out_b, (float*)d_out);
}

// Round 4
// 573.196 us; speedup vs baseline: 2.2144x; 2.2144x over previous
//
#include <hip/hip_runtime.h>

#define NG 1024
#define GN_EPS 1e-5f
#define BSHIFT 7  // 128 nodes per bucket

__device__ __forceinline__ float bf2f(unsigned short u) {
  union { float f; unsigned int i; } c;
  c.i = ((unsigned int)u) << 16;
  return c.f;
}
__device__ __forceinline__ unsigned short f2bf(float f) {
  union { float f; unsigned int i; } c;
  c.f = f;
  unsigned int b = c.i;
  b += 0x7fffu + ((b >> 16) & 1u);  // RNE
  return (unsigned short)(b >> 16);
}
__device__ __forceinline__ void f4red(float4& a, int mask) {
  a.x += __shfl_xor(a.x, mask);
  a.y += __shfl_xor(a.y, mask);
  a.z += __shfl_xor(a.z, mask);
  a.w += __shfl_xor(a.w, mask);
}

// ---------------- graph boundaries from sorted batch ----------------
__global__ void k_bounds(const int* __restrict__ batch, int* __restrict__ goff, int N) {
  int i = blockIdx.x * blockDim.x + threadIdx.x;
  if (i >= N) return;
  int b = batch[i];
  int pb = (i == 0) ? -1 : batch[i - 1];
  for (int g = pb + 1; g <= b; ++g) goff[g] = i;
  if (i == N - 1) {
    for (int g = b + 1; g <= NG; ++g) goff[g] = N;
  }
}

// ---------------- bucketed CSR build ----------------
__global__ void k_hist(const int* __restrict__ dst, int* __restrict__ bucketCnt,
                       int E, int B) {
  __shared__ int h[1024];
  for (int i = threadIdx.x; i < B; i += 256) h[i] = 0;
  __syncthreads();
  for (int e = blockIdx.x * 256 + threadIdx.x; e < E; e += gridDim.x * 256)
    atomicAdd(&h[dst[e] >> BSHIFT], 1);
  __syncthreads();
  for (int i = threadIdx.x; i < B; i += 256)
    if (h[i]) atomicAdd(&bucketCnt[i], h[i]);
}

__global__ void k_bscan(const int* __restrict__ bucketCnt, int* __restrict__ bucketOff,
                        int* __restrict__ bucketCur, int B) {
  __shared__ int lds[1024];
  int t = threadIdx.x;
  int v = (t < B) ? bucketCnt[t] : 0;
  lds[t] = v;
  __syncthreads();
  for (int off = 1; off < 1024; off <<= 1) {
    int u = (t >= off) ? lds[t - off] : 0;
    __syncthreads();
    lds[t] += u;
    __syncthreads();
  }
  if (t < B) {
    int ex = lds[t] - v;
    bucketOff[t] = ex;
    bucketCur[t] = ex;
  }
}

// multisplit scatter: per-block LDS hist -> one global reservation atomic per
// (block,bucket) -> LDS-atomic placement into the reserved contiguous runs.
__global__ __launch_bounds__(256) void k_binscatter(
    const int* __restrict__ src, const int* __restrict__ dst,
    int* __restrict__ bucketCur, unsigned int* __restrict__ ebuf,
    int E, int B, int C) {
  __shared__ int h[1024];
  __shared__ int cur[1024];
  int s = blockIdx.x * C;
  int e = min(s + C, E);
  if (s >= E) return;
  int t = threadIdx.x;
  for (int i = t; i < B; i += 256) h[i] = 0;
  __syncthreads();
  for (int k = s + t; k < e; k += 256) atomicAdd(&h[dst[k] >> BSHIFT], 1);
  __syncthreads();
  for (int i = t; i < B; i += 256) {
    int c = h[i];
    cur[i] = c ? atomicAdd(&bucketCur[i], c) : 0;
  }
  __syncthreads();
  for (int k = s + t; k < e; k += 256) {
    int d = dst[k];
    int b = d >> BSHIFT;
    int pos = atomicAdd(&cur[b], 1);
    ebuf[pos] = ((unsigned int)(d & 127) << 24) | (unsigned int)src[k];
  }
}

// one block per bucket: local degree hist + scan in LDS -> rowptr; scatter col
// within the bucket's ~16KB L2-resident slice.
__global__ void k_bucket_fill(const unsigned int* __restrict__ ebuf,
                              const int* __restrict__ bucketOff,
                              int* __restrict__ rowptr, int* __restrict__ col,
                              int N, int E, int B) {
  __shared__ int deg[128];
  __shared__ int cur[128];
  int b = blockIdx.x;
  int s = bucketOff[b];
  int e = (b + 1 < B) ? bucketOff[b + 1] : E;
  int t = threadIdx.x;
  int base = b << BSHIFT;
  if (t < 128) deg[t] = 0;
  __syncthreads();
  for (int k = s + t; k < e; k += 256) atomicAdd(&deg[ebuf[k] >> 24], 1);
  __syncthreads();
  if (t == 0) {
    int acc = s;
    for (int i = 0; i < 128; ++i) {
      int d = deg[i];
      deg[i] = acc;
      acc += d;
    }
  }
  __syncthreads();
  if (t < 128) {
    cur[t] = deg[t];
    int idx = base + t;
    if (idx <= N) rowptr[idx] = deg[t];
  }
  __syncthreads();
  for (int k = s + t; k < e; k += 256) {
    unsigned int p = ebuf[k];
    int pos = atomicAdd(&cur[p >> 24], 1);
    col[pos] = (int)(p & 0x00ffffffu);
  }
}

// ---------------- GraphNorm: f32 out + bf16 mirror for the gather ----------------
template <int F>
__global__ void k_gn(const float* x, float* out, unsigned short* outbf,
                     const int* __restrict__ goff,
                     const float* __restrict__ w, const float* __restrict__ b,
                     const float* __restrict__ ms) {
  constexpr int NPW = 256 / F;
  __shared__ float r1[256], r2[256];
  __shared__ float sA[F], sB[F];
  int g = blockIdx.x;
  int s = goff[g], e = goff[g + 1];
  int t = threadIdx.x;
  int f = t % F, sub = t / F;
  float s1 = 0.f, s2 = 0.f;
  for (int i = s + sub; i < e; i += NPW) {
    float v = x[i * F + f];
    s1 += v;
    s2 += v * v;
  }
  r1[t] = s1;
  r2[t] = s2;
  __syncthreads();
  if (t < F) {
    float S1 = 0.f, S2 = 0.f;
    for (int k = 0; k < NPW; ++k) {
      S1 += r1[k * F + t];
      S2 += r2[k * F + t];
    }
    float cnt = (float)max(e - s, 1);
    float mean = S1 / cnt, m2 = S2 / cnt;
    float m = ms[t];
    float var = m2 + mean * mean * m * (m - 2.f);  // E[(x-mean*ms)^2]
    float rsq = rsqrtf(var + GN_EPS);
    float Av = w[t] * rsq;
    sA[t] = Av;
    sB[t] = b[t] - mean * m * Av;
  }
  __syncthreads();
  float Af = sA[f], Bf = sB[f];
  for (int i = s + sub; i < e; i += NPW) {
    float v = x[i * F + f] * Af + Bf;
    out[i * F + f] = v;
    outbf[i * F + f] = f2bf(v);
  }
}

// ---------------- GraphConv ----------------
template <int FIN>
__global__ __launch_bounds__(256) void k_conv(
    const float* __restrict__ hin, const unsigned short* __restrict__ hbf,
    float* __restrict__ hout,
    const int* __restrict__ rowptr, const int* __restrict__ col,
    const float* __restrict__ wrel, const float* __restrict__ brel,
    const float* __restrict__ wroot, int N) {
  constexpr int PAD = FIN + 4;
  constexpr int NSLOT = (FIN == 64) ? 4 : 16;
  __shared__ float aggL[64 * PAD];
  int tile = blockIdx.x;
  int lane = threadIdx.x & 63;
  int w = __builtin_amdgcn_readfirstlane(threadIdx.x >> 6);

  int q = (FIN == 64) ? (lane & 15) : (lane & 3);
  int slot = (FIN == 64) ? (lane >> 4) : (lane >> 2);

  for (int nl = 0; nl < 16; ++nl) {
    int r = w * 16 + nl;
    int n = tile * 64 + r;
    float4 a0 = make_float4(0.f, 0.f, 0.f, 0.f);
    float4 a1 = make_float4(0.f, 0.f, 0.f, 0.f);
    if (n < N) {
      int s = rowptr[n], e = rowptr[n + 1];
      int k = s + slot;
      for (; k + NSLOT < e; k += 2 * NSLOT) {
        int nb0 = col[k];
        int nb1 = col[k + NSLOT];
        ushort4 v0 = *(const ushort4*)&hbf[(size_t)nb0 * FIN + q * 4];
        ushort4 v1 = *(const ushort4*)&hbf[(size_t)nb1 * FIN + q * 4];
        a0.x += bf2f(v0.x); a0.y += bf2f(v0.y); a0.z += bf2f(v0.z); a0.w += bf2f(v0.w);
        a1.x += bf2f(v1.x); a1.y += bf2f(v1.y); a1.z += bf2f(v1.z); a1.w += bf2f(v1.w);
      }
      if (k < e) {
        int nb = col[k];
        ushort4 v = *(const ushort4*)&hbf[(size_t)nb * FIN + q * 4];
        a0.x += bf2f(v.x); a0.y += bf2f(v.y); a0.z += bf2f(v.z); a0.w += bf2f(v.w);
      }
    }
    a0.x += a1.x; a0.y += a1.y; a0.z += a1.z; a0.w += a1.w;
    if (FIN == 64) {
      f4red(a0, 16);
      f4red(a0, 32);
    } else {
      f4red(a0, 4);
      f4red(a0, 8);
      f4red(a0, 16);
      f4red(a0, 32);
    }
    if (slot == 0) *(float4*)&aggL[r * PAD + q * 4] = a0;
  }
  __syncthreads();

  int n = tile * 64 + lane;
  if (n >= N) return;
  int wbase = w * 16;
  float accR[16], accT[16];
#pragma unroll
  for (int j = 0; j < 16; ++j) {
    accR[j] = 0.f;
    accT[j] = 0.f;
  }
#pragma unroll 2
  for (int fq = 0; fq < FIN / 4; ++fq) {
    float4 qa = *(const float4*)&aggL[lane * PAD + fq * 4];
    float4 qh = *(const float4*)&hin[(size_t)n * FIN + fq * 4];
#pragma unroll
    for (int j = 0; j < 16; ++j) {
      int o = wbase + j;
      const float* wr = &wrel[o * FIN + fq * 4];
      const float* wt = &wroot[o * FIN + fq * 4];
      accR[j] += wr[0] * qa.x + wr[1] * qa.y + wr[2] * qa.z + wr[3] * qa.w;
      accT[j] += wt[0] * qh.x + wt[1] * qh.y + wt[2] * qh.z + wt[3] * qh.w;
    }
  }
#pragma unroll
  for (int qq = 0; qq < 4; ++qq) {
    float4 rv;
    float* rr = (float*)&rv;
#pragma unroll
    for (int jj = 0; jj < 4; ++jj) {
      int j = qq * 4 + jj;
      float v = accR[j] + accT[j] + brel[wbase + j];
      rr[jj] = fmaxf(v, 0.f);
    }
    *(float4*)&hout[(size_t)n * 64 + wbase + qq * 4] = rv;
  }
}

// ---------------- mean-pool + dense(relu) + out + softmax ----------------
__global__ void k_final(const float* __restrict__ h, const int* __restrict__ goff,
                        const float* __restrict__ dw, const float* __restrict__ db,
                        const float* __restrict__ ow, const float* __restrict__ ob,
                        float* __restrict__ out) {
  __shared__ float red[256];
  __shared__ float pl[64];
  __shared__ float gl[64];
  int g = blockIdx.x;
  int s = goff[g], e = goff[g + 1];
  int t = threadIdx.x;
  int f = t & 63, sub = t >> 6;
  float s1 = 0.f;
  for (int i = s + sub; i < e; i += 4) s1 += h[i * 64 + f];
  red[t] = s1;
  __syncthreads();
  if (t < 64) {
    float S = red[t] + red[64 + t] + red[128 + t] + red[192 + t];
    float cnt = (float)max(e - s, 1);
    pl[t] = S / cnt;
  }
  __syncthreads();
  if (t < 64) {
    float acc = db[t];
#pragma unroll 8
    for (int k = 0; k < 64; ++k) acc += dw[t * 64 + k] * pl[k];
    gl[t] = fmaxf(acc, 0.f);
  }
  __syncthreads();
  if (t == 0) {
    float l0 = ob[0], l1 = ob[1];
    for (int k = 0; k < 64; ++k) {
      l0 += ow[k] * gl[k];
      l1 += ow[64 + k] * gl[k];
    }
    float m = fmaxf(l0, l1);
    float e0 = expf(l0 - m), e1 = expf(l1 - m);
    float inv = 1.f / (e0 + e1);
    out[g * 2 + 0] = e0 * inv;
    out[g * 2 + 1] = e1 * inv;
  }
}

extern "C" void kernel_launch(void* const* d_in, const int* in_sizes, int n_in,
                              void* d_out, int out_size, void* d_ws, size_t ws_size,
                              hipStream_t stream) {
  const float* x = (const float*)d_in[0];
  const int* ei = (const int*)d_in[1];
  const int* batch = (const int*)d_in[2];
  const float* gn0_w = (const float*)d_in[3];
  const float* gn0_b = (const float*)d_in[4];
  const float* gn0_ms = (const float*)d_in[5];
  const float* gn1_w = (const float*)d_in[6];
  const float* gn1_b = (const float*)d_in[7];
  const float* gn1_ms = (const float*)d_in[8];
  const float* gn2_w = (const float*)d_in[9];
  const float* gn2_b = (const float*)d_in[10];
  const float* gn2_ms = (const float*)d_in[11];
  const float* w1_rel = (const float*)d_in[12];
  const float* b1 = (const float*)d_in[13];
  const float* w1_root = (const float*)d_in[14];
  const float* w2_rel = (const float*)d_in[15];
  const float* b2 = (const float*)d_in[16];
  const float* w2_root = (const float*)d_in[17];
  const float* w3_rel = (const float*)d_in[18];
  const float* b3 = (const float*)d_in[19];
  const float* w3_root = (const float*)d_in[20];
  const float* dense_w = (const float*)d_in[21];
  const float* dense_b = (const float*)d_in[22];
  const float* out_w = (const float*)d_in[23];
  const float* out_b = (const float*)d_in[24];

  int N = in_sizes[2];
  int E = in_sizes[1] / 2;
  int B = (N >> BSHIFT) + 1;

  char* ws = (char*)d_ws;
  auto alloc = [&](size_t bytes) {
    char* p = ws;
    ws += (bytes + 255) & ~(size_t)255;
    return p;
  };
  int* rowptr = (int*)alloc(((size_t)N + 1) * 4);
  int* goff = (int*)alloc((NG + 1) * 4);
  int* bucketCnt = (int*)alloc((size_t)B * 4);
  int* bucketOff = (int*)alloc((size_t)B * 4);
  int* bucketCur = (int*)alloc((size_t)B * 4);
  int* col = (int*)alloc((size_t)E * 4);
  size_t hbytes = (size_t)N * 64 * 4;
  size_t ebytes = (size_t)E * 4;  // u32 entries
  char* hA_raw = (char*)alloc(hbytes > ebytes ? hbytes : ebytes);  // hA aliases ebuf
  float* hA = (float*)hA_raw;
  unsigned int* ebuf = (unsigned int*)hA_raw;
  float* hB = (float*)alloc(hbytes);
  unsigned short* hbf = (unsigned short*)alloc((size_t)N * 64 * 2);

  const int* src = ei;
  const int* dst = ei + E;

  hipMemsetAsync(bucketCnt, 0, (size_t)B * 4, stream);
  k_bounds<<<(N + 255) / 256, 256, 0, stream>>>(batch, goff, N);
  k_hist<<<256, 256, 0, stream>>>(dst, bucketCnt, E, B);
  k_bscan<<<1, 1024, 0, stream>>>(bucketCnt, bucketOff, bucketCur, B);
  int nbs = 192;
  int C = (E + nbs - 1) / nbs;
  k_binscatter<<<nbs, 256, 0, stream>>>(src, dst, bucketCur, ebuf, E, B, C);
  k_bucket_fill<<<B, 256, 0, stream>>>(ebuf, bucketOff, rowptr, col, N, E, B);

  int tiles = (N + 63) / 64;
  k_gn<16><<<NG, 256, 0, stream>>>(x, hA, hbf, goff, gn0_w, gn0_b, gn0_ms);
  k_conv<16><<<tiles, 256, 0, stream>>>(hA, hbf, hB, rowptr, col, w1_rel, b1, w1_root, N);
  k_gn<64><<<NG, 256, 0, stream>>>(hB, hB, hbf, goff, gn1_w, gn1_b, gn1_ms);
  k_conv<64><<<tiles, 256, 0, stream>>>(hB, hbf, hA, rowptr, col, w2_rel, b2, w2_root, N);
  k_gn<64><<<NG, 256, 0, stream>>>(hA, hA, hbf, goff, gn2_w, gn2_b, gn2_ms);
  k_conv<64><<<tiles, 256, 0, stream>>>(hA, hbf, hB, rowptr, col, w3_rel, b3, w3_root, N);
  k_final<<<NG, 256, 0, stream>>>(hB, goff, dense_w, dense_b, out_w, out_b, (float*)d_out);
}